// Round 1
// baseline (1665.692 us; speedup 1.0000x reference)
//
#include <hip/hip_runtime.h>

#define EPS_ 1e-4f

// ---------------------------------------------------------------------------
// Kernel 1: 8x8 average pool.  sdf (2,1024,1024) -> pooled (2,128,128)
// ---------------------------------------------------------------------------
__global__ void pool_kernel(const float* __restrict__ sdf, float* __restrict__ pooled) {
    int t = blockIdx.x * blockDim.x + threadIdx.x;  // 0..32767
    int c = t >> 14;
    int rem = t & 16383;
    int R = rem >> 7;
    int C = rem & 127;
    const float* base = sdf + c * 1048576 + (R * 8) * 1024 + C * 8;
    float sum = 0.f;
#pragma unroll
    for (int r = 0; r < 8; r++) {
        const float4* p = (const float4*)(base + r * 1024);
        float4 a = p[0];
        float4 b = p[1];
        sum += a.x + a.y + a.z + a.w + b.x + b.y + b.z + b.w;
    }
    pooled[t] = sum * (1.f / 64.f);
}

// ---------------------------------------------------------------------------
// Kernel 2: 5x5 conv, 2->16 ch, pad 2.  pooled (2,128,128) -> A [(y*128+x)*16+f]
// (channel-last so the interp kernel can read 4 x float4 per corner)
// ---------------------------------------------------------------------------
__global__ void conv_kernel(const float* __restrict__ pooled,
                            const float* __restrict__ conv_w,
                            const float* __restrict__ conv_b,
                            float* __restrict__ A) {
    int t = blockIdx.x * blockDim.x + threadIdx.x;  // 0..16383
    int y = t >> 7, x = t & 127;
    float acc[16];
#pragma unroll
    for (int f = 0; f < 16; f++) acc[f] = conv_b[f];
#pragma unroll
    for (int c = 0; c < 2; c++) {
#pragma unroll
        for (int ky = 0; ky < 5; ky++) {
            int yy = y + ky - 2;
            if (yy < 0 || yy > 127) continue;
#pragma unroll
            for (int kx = 0; kx < 5; kx++) {
                int xx = x + kx - 2;
                if (xx < 0 || xx > 127) continue;
                float v = pooled[c * 16384 + yy * 128 + xx];
                int wbase = c * 25 + ky * 5 + kx;
#pragma unroll
                for (int f = 0; f < 16; f++)
                    acc[f] = fmaf(v, conv_w[f * 50 + wbase], acc[f]);
            }
        }
    }
    float4* out4 = (float4*)(A + t * 16);
#pragma unroll
    for (int q = 0; q < 4; q++)
        out4[q] = make_float4(acc[4 * q], acc[4 * q + 1], acc[4 * q + 2], acc[4 * q + 3]);
}

// ---------------------------------------------------------------------------
// Kernel 3: per-point bilinear interp + 4-layer MLP.
// Activations in LDS [k][tid] (runtime-k reads); output j fully unrolled into
// register accumulators (compile-time indices only -> stays in VGPRs).
// Weight reads are wave-uniform -> scalar loads, SGPR operands to v_fmac.
// ---------------------------------------------------------------------------
__global__ void __launch_bounds__(64) mlp_kernel(
    const float* __restrict__ x, const float* __restrict__ s,
    const float* __restrict__ sse, const float* __restrict__ A,
    const float* __restrict__ w1, const float* __restrict__ b1,
    const float* __restrict__ w2, const float* __restrict__ b2,
    const float* __restrict__ w3, const float* __restrict__ b3,
    const float* __restrict__ w4, const float* __restrict__ b4,
    float* __restrict__ out) {
    __shared__ float act[128 * 64];  // 32 KB, [k][tid]
    const int tid = threadIdx.x;
    const long i = (long)blockIdx.x * 64 + tid;  // grid covers N exactly

    // ---- gather inputs ----
    float2 xv = *(const float2*)(x + 2 * i);
    float sv = s[i];

    float gx = fminf(fmaxf(xv.x, EPS_), 1.f - EPS_) * 127.f;
    float gy = fminf(fmaxf(xv.y, EPS_), 1.f - EPS_) * 127.f;
    float fx0 = floorf(gx), fy0 = floorf(gy);
    int x0 = (int)fx0, y0 = (int)fy0;
    int x1i = min(x0 + 1, 127), y1i = min(y0 + 1, 127);
    float wx = gx - fx0, wy = gy - fy0;
    float w00 = (1.f - wx) * (1.f - wy);
    float w10 = wx * (1.f - wy);
    float w01 = (1.f - wx) * wy;
    float w11 = wx * wy;

    const float4* A4 = (const float4*)A;
    int c00 = (y0 * 128 + x0) * 4;
    int c10 = (y0 * 128 + x1i) * 4;
    int c01 = (y1i * 128 + x0) * 4;
    int c11 = (y1i * 128 + x1i) * 4;

    act[0 * 64 + tid] = xv.x;
    act[1 * 64 + tid] = xv.y;
    act[2 * 64 + tid] = sv;

    const float2* sp = (const float2*)(sse + 50 * i);
#pragma unroll
    for (int k = 0; k < 25; k++) {
        float2 v = sp[k];
        act[(3 + 2 * k) * 64 + tid] = v.x;
        act[(4 + 2 * k) * 64 + tid] = v.y;
    }

#pragma unroll
    for (int cc = 0; cc < 4; cc++) {
        float4 f00 = A4[c00 + cc];
        float4 f10 = A4[c10 + cc];
        float4 f01 = A4[c01 + cc];
        float4 f11 = A4[c11 + cc];
        float r0 = f00.x * w00 + f10.x * w10 + f01.x * w01 + f11.x * w11;
        float r1 = f00.y * w00 + f10.y * w10 + f01.y * w01 + f11.y * w11;
        float r2 = f00.z * w00 + f10.z * w10 + f01.z * w01 + f11.z * w11;
        float r3 = f00.w * w00 + f10.w * w10 + f01.w * w01 + f11.w * w11;
        act[(53 + 4 * cc + 0) * 64 + tid] = r0;
        act[(53 + 4 * cc + 1) * 64 + tid] = r1;
        act[(53 + 4 * cc + 2) * 64 + tid] = r2;
        act[(53 + 4 * cc + 3) * 64 + tid] = r3;
    }

    // ---- layer 1: 69 -> 128, relu ----
    float a1[128];
#pragma unroll
    for (int j = 0; j < 128; j++) a1[j] = b1[j];
    for (int k = 0; k < 69; k++) {
        float hk = act[k * 64 + tid];
        const float* wr = w1 + k * 128;
#pragma unroll
        for (int j = 0; j < 128; j++) a1[j] = fmaf(hk, wr[j], a1[j]);
    }
#pragma unroll
    for (int j = 0; j < 128; j++) act[j * 64 + tid] = fmaxf(a1[j], 0.f);

    // ---- layer 2: 128 -> 128, relu ----
    float a2[128];
#pragma unroll
    for (int j = 0; j < 128; j++) a2[j] = b2[j];
    for (int k = 0; k < 128; k++) {
        float hk = act[k * 64 + tid];
        const float* wr = w2 + k * 128;
#pragma unroll
        for (int j = 0; j < 128; j++) a2[j] = fmaf(hk, wr[j], a2[j]);
    }
#pragma unroll
    for (int j = 0; j < 128; j++) act[j * 64 + tid] = fmaxf(a2[j], 0.f);

    // ---- layer 3: 128 -> 96 ----
    float a3[96];
#pragma unroll
    for (int j = 0; j < 96; j++) a3[j] = b3[j];
    for (int k = 0; k < 128; k++) {
        float hk = act[k * 64 + tid];
        const float* wr = w3 + k * 96;
#pragma unroll
        for (int j = 0; j < 96; j++) a3[j] = fmaf(hk, wr[j], a3[j]);
    }

    // ---- layer 4: 96 -> 1 (relu folded in) ----
    float o = b4[0];
#pragma unroll
    for (int k = 0; k < 96; k++) o = fmaf(fmaxf(a3[k], 0.f), w4[k], o);
    out[i] = o;
}

// ---------------------------------------------------------------------------
extern "C" void kernel_launch(void* const* d_in, const int* in_sizes, int n_in,
                              void* d_out, int out_size, void* d_ws, size_t ws_size,
                              hipStream_t stream) {
    const float* x      = (const float*)d_in[0];
    const float* s      = (const float*)d_in[1];
    const float* sse    = (const float*)d_in[2];
    const float* sdf    = (const float*)d_in[3];
    const float* conv_w = (const float*)d_in[4];
    const float* conv_b = (const float*)d_in[5];
    const float* w1     = (const float*)d_in[6];
    const float* b1     = (const float*)d_in[7];
    const float* w2     = (const float*)d_in[8];
    const float* b2     = (const float*)d_in[9];
    const float* w3     = (const float*)d_in[10];
    const float* b3     = (const float*)d_in[11];
    const float* w4     = (const float*)d_in[12];
    const float* b4     = (const float*)d_in[13];
    float* out = (float*)d_out;

    float* pooled = (float*)d_ws;           // 2*128*128 = 32768 floats
    float* A      = pooled + 32768;         // 128*128*16 = 262144 floats

    pool_kernel<<<128, 256, 0, stream>>>(sdf, pooled);
    conv_kernel<<<64, 256, 0, stream>>>(pooled, conv_w, conv_b, A);
    mlp_kernel<<<15625, 64, 0, stream>>>(x, s, sse, A,
                                         w1, b1, w2, b2, w3, b3, w4, b4, out);
}

// Round 2
// 292.657 us; speedup vs baseline: 5.6916x; 5.6916x over previous
//
#include <hip/hip_runtime.h>

#define EPS_ 1e-4f

typedef _Float16 f16;
typedef _Float16 f16x8 __attribute__((ext_vector_type(8)));
typedef _Float16 f16x4 __attribute__((ext_vector_type(4)));
typedef float f32x4_t __attribute__((ext_vector_type(4)));

__device__ inline f32x4_t mfma16(f16x8 a, f16x8 b, f32x4_t c) {
    return __builtin_amdgcn_mfma_f32_16x16x32_f16(a, b, c, 0, 0, 0);
}

__device__ inline f16x8 cvt8(f32x4_t lo, f32x4_t hi) {
    f16x8 r;
    r[0] = (f16)lo.x; r[1] = (f16)lo.y; r[2] = (f16)lo.z; r[3] = (f16)lo.w;
    r[4] = (f16)hi.x; r[5] = (f16)hi.y; r[6] = (f16)hi.z; r[7] = (f16)hi.w;
    return r;
}

__device__ inline f16x8 zero8() {
    f16x8 r;
#pragma unroll
    for (int i = 0; i < 8; i++) r[i] = (f16)0.f;
    return r;
}

// ---------------------------------------------------------------------------
// Kernel 1: 8x8 average pool.  sdf (2,1024,1024) -> pooled (2,128,128)
// ---------------------------------------------------------------------------
__global__ void pool_kernel(const float* __restrict__ sdf, float* __restrict__ pooled) {
    int t = blockIdx.x * blockDim.x + threadIdx.x;
    int c = t >> 14;
    int rem = t & 16383;
    int R = rem >> 7;
    int C = rem & 127;
    const float* base = sdf + c * 1048576 + (R * 8) * 1024 + C * 8;
    float sum = 0.f;
#pragma unroll
    for (int r = 0; r < 8; r++) {
        const float4* p = (const float4*)(base + r * 1024);
        float4 a = p[0];
        float4 b = p[1];
        sum += a.x + a.y + a.z + a.w + b.x + b.y + b.z + b.w;
    }
    pooled[t] = sum * (1.f / 64.f);
}

// ---------------------------------------------------------------------------
// Kernel 2: 5x5 conv, 2->16 ch, pad 2. pooled (2,128,128) -> A [(y*128+x)*16+f] f32
// ---------------------------------------------------------------------------
__global__ void conv_kernel(const float* __restrict__ pooled,
                            const float* __restrict__ conv_w,
                            const float* __restrict__ conv_b,
                            float* __restrict__ A) {
    int t = blockIdx.x * blockDim.x + threadIdx.x;
    int y = t >> 7, x = t & 127;
    float acc[16];
#pragma unroll
    for (int f = 0; f < 16; f++) acc[f] = conv_b[f];
#pragma unroll
    for (int c = 0; c < 2; c++) {
#pragma unroll
        for (int ky = 0; ky < 5; ky++) {
            int yy = y + ky - 2;
            if (yy < 0 || yy > 127) continue;
#pragma unroll
            for (int kx = 0; kx < 5; kx++) {
                int xx = x + kx - 2;
                if (xx < 0 || xx > 127) continue;
                float v = pooled[c * 16384 + yy * 128 + xx];
                int wbase = c * 25 + ky * 5 + kx;
#pragma unroll
                for (int f = 0; f < 16; f++)
                    acc[f] = fmaf(v, conv_w[f * 50 + wbase], acc[f]);
            }
        }
    }
    float4* out4 = (float4*)(A + t * 16);
#pragma unroll
    for (int q = 0; q < 4; q++)
        out4[q] = make_float4(acc[4 * q], acc[4 * q + 1], acc[4 * q + 2], acc[4 * q + 3]);
}

// ---------------------------------------------------------------------------
// Kernel 3: pre-pack weights into per-lane MFMA A-fragments (f16).
// Feature (k) order: 0,1=x  2=s  3..52=sse  53..63=0  64..79=interp  80=bias  81..95=0
// frag f: f<24 -> w1 (mf=f/3, kc=f%3);  24..55 -> w2 (mf,kc = /4,%4);  56..79 -> w3
// A-frag layout: lane l holds W[out=16*mf+(l&15)][k=32*kc+8*(l>>4)+i], i=0..7
// ---------------------------------------------------------------------------
__global__ void pack_kernel(const float* __restrict__ w1, const float* __restrict__ b1,
                            const float* __restrict__ w2, const float* __restrict__ w3,
                            f16* __restrict__ frags) {
    int t = blockIdx.x * blockDim.x + threadIdx.x;
    if (t >= 80 * 64) return;
    int f = t >> 6, lane = t & 63;
    int g = lane >> 4, col = lane & 15;
    f16 v[8];
    if (f < 24) {
        int mf = f / 3, kc = f % 3;
        int o = mf * 16 + col;
#pragma unroll
        for (int i = 0; i < 8; i++) {
            int k = kc * 32 + g * 8 + i;
            float val = 0.f;
            if (k <= 52) val = w1[k * 128 + o];
            else if (k >= 64 && k <= 79) val = w1[(k - 11) * 128 + o];
            else if (k == 80) val = b1[o];
            v[i] = (f16)val;
        }
    } else if (f < 56) {
        int ff = f - 24, mf = ff >> 2, kc = ff & 3;
        int o = mf * 16 + col;
#pragma unroll
        for (int i = 0; i < 8; i++) {
            int k = kc * 32 + g * 8 + i;
            v[i] = (f16)w2[k * 128 + o];
        }
    } else {
        int ff = f - 56, mf = ff >> 2, kc = ff & 3;
        int o = mf * 16 + col;
#pragma unroll
        for (int i = 0; i < 8; i++) {
            int k = kc * 32 + g * 8 + i;
            v[i] = (f16)w3[k * 96 + o];
        }
    }
    f16* dst = frags + (f * 64 + lane) * 8;
#pragma unroll
    for (int i = 0; i < 8; i++) dst[i] = v[i];
}

// ---------------------------------------------------------------------------
// Kernel 4: fused interp + MLP via f16 MFMA.  One wave per block, 16 pts/batch.
// Weights live in registers as A-frags; acts built as B-frags (LDS staged).
// C[out][pt]: lane holds out = 16*mf + 4*(l>>4) + r, pt = l&15.
// ---------------------------------------------------------------------------
__global__ void __launch_bounds__(64, 1) mlp_kernel(
    const float* __restrict__ x, const float* __restrict__ s,
    const float* __restrict__ sse, const float* __restrict__ Amat,
    const f16* __restrict__ frags,
    const float* __restrict__ b2, const float* __restrict__ b3,
    const float* __restrict__ w4, const float* __restrict__ b4,
    float* __restrict__ out) {
    __shared__ float stage[16 * 84];   // f32 staged inputs, row stride 84 dwords
    __shared__ f16 acth[16 * 128];     // activations [pt][k], XOR-swizzled
    __shared__ float bias2[128], bias3[96], w4l[96];

    const int lane = threadIdx.x;
    const int g = lane >> 4, col = lane & 15;
    const int swz = (col & 7) << 3;    // swizzle in f16-index units (bits 3..5)

    // ---- load weight fragments into registers (once per block) ----
    f16x8 w1f[8][3], w2f[8][4], w3f[6][4];
    {
        const f16* fb = frags + lane * 8;
#pragma unroll
        for (int mf = 0; mf < 8; mf++)
#pragma unroll
            for (int kc = 0; kc < 3; kc++)
                w1f[mf][kc] = *(const f16x8*)(fb + (mf * 3 + kc) * 512);
#pragma unroll
        for (int mf = 0; mf < 8; mf++)
#pragma unroll
            for (int kc = 0; kc < 4; kc++)
                w2f[mf][kc] = *(const f16x8*)(fb + (24 + mf * 4 + kc) * 512);
#pragma unroll
        for (int mf = 0; mf < 6; mf++)
#pragma unroll
            for (int kc = 0; kc < 4; kc++)
                w3f[mf][kc] = *(const f16x8*)(fb + (56 + mf * 4 + kc) * 512);
    }
    // ---- stage biases / w4 (single wave: LDS ops are wave-ordered) ----
    for (int i = lane; i < 128; i += 64) bias2[i] = b2[i];
    for (int i = lane; i < 96; i += 64) { bias3[i] = b3[i]; w4l[i] = w4[i]; }
    float b4v = b4[0];
    // zero the never-written stage columns 53..63
    for (int i = lane; i < 256; i += 64) {
        int r = i >> 4, c = i & 15;
        if (c < 11) stage[r * 84 + 53 + c] = 0.f;
    }
    __syncthreads();

    const int wtotal = 62500;          // 1e6 / 16
    // prefetch registers
    f32x4_t sseR[4];
    float xR, sR, xxR, yyR;

    auto LOADB = [&](int wbi) {
        long p0 = (long)wbi * 16;
        const f32x4_t* sb = (const f32x4_t*)(sse + p0 * 50);
#pragma unroll
        for (int r = 0; r < 4; r++) {
            int li4 = r * 64 + lane;
            li4 = li4 < 200 ? li4 : 199;
            sseR[r] = sb[li4];
        }
        xR = x[p0 * 2 + (lane & 31)];
        sR = s[p0 + col];
        xxR = x[(p0 + (lane >> 2)) * 2];
        yyR = x[(p0 + (lane >> 2)) * 2 + 1];
    };

    int wb = blockIdx.x;
    if (wb < wtotal) LOADB(wb);

    for (; wb < wtotal; wb += gridDim.x) {
        const long p0 = (long)wb * 16;

        // ---- STORE staged inputs ----
#pragma unroll
        for (int r = 0; r < 4; r++) {
            int li4 = r * 64 + lane;
            li4 = li4 < 200 ? li4 : 199;
            int base = li4 * 4;
#pragma unroll
            for (int c = 0; c < 4; c++) {
                int ii = base + c;
                int p = ii / 50;
                int k = ii - p * 50 + 3;
                stage[p * 84 + k] = sseR[r][c];
            }
        }
        if (lane < 32) stage[(lane >> 1) * 84 + (lane & 1)] = xR;
        if (lane < 16) stage[col * 84 + 2] = sR;

        // ---- issue interp gathers (lane = pt*4 + q) ----
        f32x4_t aR0, aR1, aR2, aR3;
        float wqR;
        {
            int q = lane & 3;
            float gx = fminf(fmaxf(xxR, EPS_), 1.f - EPS_) * 127.f;
            float gy = fminf(fmaxf(yyR, EPS_), 1.f - EPS_) * 127.f;
            float fx0 = floorf(gx), fy0 = floorf(gy);
            int ix0 = (int)fx0, iy0 = (int)fy0;
            int ix1 = min(ix0 + 1, 127), iy1 = min(iy0 + 1, 127);
            float wx = gx - fx0, wy = gy - fy0;
            int cx = (q & 1) ? ix1 : ix0;
            int cy = (q & 2) ? iy1 : iy0;
            wqR = ((q & 1) ? wx : (1.f - wx)) * ((q & 2) ? wy : (1.f - wy));
            const f32x4_t* Ab = (const f32x4_t*)(Amat + (cy * 128 + cx) * 16);
            aR0 = Ab[0]; aR1 = Ab[1]; aR2 = Ab[2]; aR3 = Ab[3];
        }

        // ---- prefetch next batch ----
        int wbn = wb + gridDim.x;
        if (wbn < wtotal) LOADB(wbn);

        // ---- Layer 1, kc = 0,1 (pure staged data) ----
        f32x4_t acc1[8];
#pragma unroll
        for (int mf = 0; mf < 8; mf++) { acc1[mf].x = 0.f; acc1[mf].y = 0.f; acc1[mf].z = 0.f; acc1[mf].w = 0.f; }
#pragma unroll
        for (int kc = 0; kc < 2; kc++) {
            const f32x4_t* sp = (const f32x4_t*)&stage[col * 84 + kc * 32 + g * 8];
            f16x8 bf = cvt8(sp[0], sp[1]);
#pragma unroll
            for (int mf = 0; mf < 8; mf++) acc1[mf] = mfma16(w1f[mf][kc], bf, acc1[mf]);
        }

        // ---- finalize interp, write stage cols 64..79 ----
        {
            f32x4_t t0 = aR0 * wqR, t1 = aR1 * wqR, t2 = aR2 * wqR, t3 = aR3 * wqR;
#pragma unroll
            for (int c = 0; c < 4; c++) {
                t0[c] += __shfl_xor(t0[c], 1); t0[c] += __shfl_xor(t0[c], 2);
                t1[c] += __shfl_xor(t1[c], 1); t1[c] += __shfl_xor(t1[c], 2);
                t2[c] += __shfl_xor(t2[c], 1); t2[c] += __shfl_xor(t2[c], 2);
                t3[c] += __shfl_xor(t3[c], 1); t3[c] += __shfl_xor(t3[c], 2);
            }
            if ((lane & 3) == 0) {
                int pt = lane >> 2;
                f32x4_t* dp = (f32x4_t*)&stage[pt * 84 + 64];
                dp[0] = t0; dp[1] = t1; dp[2] = t2; dp[3] = t3;
            }
        }

        // ---- Layer 1, kc = 2 (interp + bias slot) ----
        {
            f16x8 bf;
            if (g < 2) {
                const f32x4_t* sp = (const f32x4_t*)&stage[col * 84 + 64 + g * 8];
                bf = cvt8(sp[0], sp[1]);
            } else if (g == 2) {
                bf = zero8();
                bf[0] = (f16)1.f;     // k=80: bias row
            } else {
                bf = zero8();
            }
#pragma unroll
            for (int mf = 0; mf < 8; mf++) acc1[mf] = mfma16(w1f[mf][2], bf, acc1[mf]);
        }
        // ---- L1 epilogue: relu -> acth (bias came via k=80 slot) ----
#pragma unroll
        for (int mf = 0; mf < 8; mf++) {
            f16x4 hv;
#pragma unroll
            for (int r = 0; r < 4; r++) hv[r] = (f16)fmaxf(acc1[mf][r], 0.f);
            *(f16x4*)&acth[(col * 128 + mf * 16 + g * 4) ^ swz] = hv;
        }

        // ---- Layer 2: 128 -> 128 ----
        f32x4_t acc2[8];
#pragma unroll
        for (int mf = 0; mf < 8; mf++) { acc2[mf].x = 0.f; acc2[mf].y = 0.f; acc2[mf].z = 0.f; acc2[mf].w = 0.f; }
#pragma unroll
        for (int kc = 0; kc < 4; kc++) {
            f16x8 bf = *(const f16x8*)&acth[(col * 128 + kc * 32 + g * 8) ^ swz];
#pragma unroll
            for (int mf = 0; mf < 8; mf++) acc2[mf] = mfma16(w2f[mf][kc], bf, acc2[mf]);
        }
#pragma unroll
        for (int mf = 0; mf < 8; mf++) {
            f32x4_t bb = *(const f32x4_t*)&bias2[mf * 16 + g * 4];
            f16x4 hv;
#pragma unroll
            for (int r = 0; r < 4; r++) hv[r] = (f16)fmaxf(acc2[mf][r] + bb[r], 0.f);
            *(f16x4*)&acth[(col * 128 + mf * 16 + g * 4) ^ swz] = hv;
        }

        // ---- Layer 3: 128 -> 96 ----
        f32x4_t acc3[6];
#pragma unroll
        for (int mf = 0; mf < 6; mf++) { acc3[mf].x = 0.f; acc3[mf].y = 0.f; acc3[mf].z = 0.f; acc3[mf].w = 0.f; }
#pragma unroll
        for (int kc = 0; kc < 4; kc++) {
            f16x8 bf = *(const f16x8*)&acth[(col * 128 + kc * 32 + g * 8) ^ swz];
#pragma unroll
            for (int mf = 0; mf < 6; mf++) acc3[mf] = mfma16(w3f[mf][kc], bf, acc3[mf]);
        }

        // ---- Layer 4: relu(h3) . w4 + b4, reduce across g-groups ----
        float partial = 0.f;
#pragma unroll
        for (int mf = 0; mf < 6; mf++) {
            f32x4_t bb = *(const f32x4_t*)&bias3[mf * 16 + g * 4];
            f32x4_t wv = *(const f32x4_t*)&w4l[mf * 16 + g * 4];
#pragma unroll
            for (int r = 0; r < 4; r++)
                partial += fmaxf(acc3[mf][r] + bb[r], 0.f) * wv[r];
        }
        partial += __shfl_xor(partial, 16);
        partial += __shfl_xor(partial, 32);
        if (g == 0) out[p0 + col] = partial + b4v;
    }
}

// ---------------------------------------------------------------------------
extern "C" void kernel_launch(void* const* d_in, const int* in_sizes, int n_in,
                              void* d_out, int out_size, void* d_ws, size_t ws_size,
                              hipStream_t stream) {
    const float* x      = (const float*)d_in[0];
    const float* s      = (const float*)d_in[1];
    const float* sse    = (const float*)d_in[2];
    const float* sdf    = (const float*)d_in[3];
    const float* conv_w = (const float*)d_in[4];
    const float* conv_b = (const float*)d_in[5];
    const float* w1     = (const float*)d_in[6];
    const float* b1     = (const float*)d_in[7];
    const float* w2     = (const float*)d_in[8];
    const float* b2     = (const float*)d_in[9];
    const float* w3     = (const float*)d_in[10];
    const float* b3     = (const float*)d_in[11];
    const float* w4     = (const float*)d_in[12];
    const float* b4     = (const float*)d_in[13];
    float* out = (float*)d_out;

    float* pooled = (float*)d_ws;            // 32768 f32  [0, 131072) bytes
    float* A      = pooled + 32768;          // 262144 f32 [131072, 1179648)
    f16*   frags  = (f16*)d_ws;              // 81920 bytes, reuses pooled region
                                             // (written by pack AFTER conv reads pooled)

    pool_kernel<<<128, 256, 0, stream>>>(sdf, pooled);
    conv_kernel<<<64, 256, 0, stream>>>(pooled, conv_w, conv_b, A);
    pack_kernel<<<20, 256, 0, stream>>>(w1, b1, w2, w3, frags);
    mlp_kernel<<<1024, 64, 0, stream>>>(x, s, sse, A, frags,
                                        b2, b3, w4, b4, out);
}

// Round 4
// 132.314 us; speedup vs baseline: 12.5890x; 2.2118x over previous
//
#include <hip/hip_runtime.h>

#define EPS_ 1e-4f

typedef _Float16 f16;
typedef _Float16 f16x8 __attribute__((ext_vector_type(8)));
typedef _Float16 f16x4 __attribute__((ext_vector_type(4)));
typedef _Float16 f16x2 __attribute__((ext_vector_type(2)));
typedef __fp16 h16x2 __attribute__((ext_vector_type(2)));
typedef float f32x4v __attribute__((ext_vector_type(4)));
typedef float f32x2v __attribute__((ext_vector_type(2)));
typedef unsigned int u32;

__device__ inline f32x4v mfma16(f16x8 a, f16x8 b, f32x4v c) {
    return __builtin_amdgcn_mfma_f32_16x16x32_f16(a, b, c, 0, 0, 0);
}
__device__ inline f16x2 pk2(float a, float b) {
    h16x2 r = __builtin_amdgcn_cvt_pkrtz(a, b);
    return __builtin_bit_cast(f16x2, r);
}
__device__ inline u32 bc32(f16x2 v) { return __builtin_bit_cast(u32, v); }

__device__ inline f16x8 zero8() {
    f16x8 r;
#pragma unroll
    for (int i = 0; i < 8; i++) r[i] = (f16)0.f;
    return r;
}

__device__ inline f16x8 cvt8x2(f32x2v a, f32x2v b, f32x2v c, f32x2v d) {
    f16x2 p0 = pk2(a.x, a.y), p1 = pk2(b.x, b.y), p2 = pk2(c.x, c.y), p3 = pk2(d.x, d.y);
    f16x8 r;
    r[0] = p0[0]; r[1] = p0[1]; r[2] = p1[0]; r[3] = p1[1];
    r[4] = p2[0]; r[5] = p2[1]; r[6] = p3[0]; r[7] = p3[1];
    return r;
}

// ---------------------------------------------------------------------------
// Kernel 1: 8x8 average pool.  sdf (2,1024,1024) -> pooled (2,128,128)
// ---------------------------------------------------------------------------
__global__ void pool_kernel(const float* __restrict__ sdf, float* __restrict__ pooled) {
    int t = blockIdx.x * blockDim.x + threadIdx.x;
    int c = t >> 14;
    int rem = t & 16383;
    int R = rem >> 7;
    int C = rem & 127;
    const float* base = sdf + c * 1048576 + (R * 8) * 1024 + C * 8;
    float sum = 0.f;
#pragma unroll
    for (int r = 0; r < 8; r++) {
        const float4* p = (const float4*)(base + r * 1024);
        float4 a = p[0];
        float4 b = p[1];
        sum += a.x + a.y + a.z + a.w + b.x + b.y + b.z + b.w;
    }
    pooled[t] = sum * (1.f / 64.f);
}

// ---------------------------------------------------------------------------
// Kernel 2: 5x5 conv, 2->16 ch, pad 2. pooled (2,128,128) -> A [(y*128+x)*16+f]
// ---------------------------------------------------------------------------
__global__ void conv_kernel(const float* __restrict__ pooled,
                            const float* __restrict__ conv_w,
                            const float* __restrict__ conv_b,
                            float* __restrict__ A) {
    int t = blockIdx.x * blockDim.x + threadIdx.x;
    int y = t >> 7, x = t & 127;
    float acc[16];
#pragma unroll
    for (int f = 0; f < 16; f++) acc[f] = conv_b[f];
#pragma unroll
    for (int c = 0; c < 2; c++) {
#pragma unroll
        for (int ky = 0; ky < 5; ky++) {
            int yy = y + ky - 2;
            if (yy < 0 || yy > 127) continue;
#pragma unroll
            for (int kx = 0; kx < 5; kx++) {
                int xx = x + kx - 2;
                if (xx < 0 || xx > 127) continue;
                float v = pooled[c * 16384 + yy * 128 + xx];
                int wbase = c * 25 + ky * 5 + kx;
#pragma unroll
                for (int f = 0; f < 16; f++)
                    acc[f] = fmaf(v, conv_w[f * 50 + wbase], acc[f]);
            }
        }
    }
    float4* out4 = (float4*)(A + t * 16);
#pragma unroll
    for (int q = 0; q < 4; q++)
        out4[q] = make_float4(acc[4 * q], acc[4 * q + 1], acc[4 * q + 2], acc[4 * q + 3]);
}

// ---------------------------------------------------------------------------
// Feature (k) order for layer 1:
//   k 0..49  = sse[0..49]      (ref w1 row 3+k)
//   k 50,51  = x0,x1           (ref rows 0,1)
//   k 52     = s               (ref row 2)
//   k 53..55 = 0
//   k 56..71 = interp ch 0..15 (ref rows 53..68)
//   k 72     = bias slot (b1)
//   k 73..95 = 0
// Kernel 3: pack weights into per-lane MFMA A-fragments (f16).
// frag f: f<24 -> w1 (mf=f/3,kc=f%3); 24..55 -> w2; 56..79 -> w3
// A-frag: lane l holds W[out=16*mf+(l&15)][k=32*kc+8*(l>>4)+i], i=0..7
// ---------------------------------------------------------------------------
__global__ void pack_kernel(const float* __restrict__ w1, const float* __restrict__ b1,
                            const float* __restrict__ w2, const float* __restrict__ w3,
                            f16* __restrict__ frags) {
    int t = blockIdx.x * blockDim.x + threadIdx.x;
    if (t >= 80 * 64) return;
    int f = t >> 6, lane = t & 63;
    int g = lane >> 4, col = lane & 15;
    f16 v[8];
    if (f < 24) {
        int mf = f / 3, kc = f % 3;
        int o = mf * 16 + col;
#pragma unroll
        for (int i = 0; i < 8; i++) {
            int k = kc * 32 + g * 8 + i;
            float val = 0.f;
            if (k < 50) val = w1[(3 + k) * 128 + o];
            else if (k == 50) val = w1[0 * 128 + o];
            else if (k == 51) val = w1[1 * 128 + o];
            else if (k == 52) val = w1[2 * 128 + o];
            else if (k >= 56 && k < 72) val = w1[(53 + (k - 56)) * 128 + o];
            else if (k == 72) val = b1[o];
            v[i] = (f16)val;
        }
    } else if (f < 56) {
        int ff = f - 24, mf = ff >> 2, kc = ff & 3;
        int o = mf * 16 + col;
#pragma unroll
        for (int i = 0; i < 8; i++) {
            int k = kc * 32 + g * 8 + i;
            v[i] = (f16)w2[k * 128 + o];
        }
    } else {
        int ff = f - 56, mf = ff >> 2, kc = ff & 3;
        int o = mf * 16 + col;
#pragma unroll
        for (int i = 0; i < 8; i++) {
            int k = kc * 32 + g * 8 + i;
            v[i] = (f16)w3[k * 96 + o];
        }
    }
    f16* dst = frags + (f * 64 + lane) * 8;
#pragma unroll
    for (int i = 0; i < 8; i++) dst[i] = v[i];
}

// ---------------------------------------------------------------------------
// Kernel 4: fused interp + MLP.  512 threads = 8 independent waves per block.
// Weight frags in LDS (80 KB, shared); each wave does 32-pt batches (2 tiles
// of 16) amortizing one weight pass over 2 MFMAs.  No main-loop barriers.
// ---------------------------------------------------------------------------
__global__ void __launch_bounds__(512, 2) mlp_kernel(
    const float* __restrict__ x, const float* __restrict__ s,
    const float* __restrict__ sse, const float* __restrict__ Amat,
    const float4* __restrict__ fragsv,
    const float* __restrict__ b2, const float* __restrict__ b3,
    const float* __restrict__ w4, const float* __restrict__ b4,
    float* __restrict__ out) {
    __shared__ f16 wlds[40960];        // 80 frags * 64 lanes * 8 f16 = 80 KB
    __shared__ f16 acth[8][2048];      // per-wave h buffer (16 pts x 128), 4 KB each
    __shared__ u32 ibuf[8][2][192];    // per-wave interp buf: 16 cols * 12 u32 (pad)
    __shared__ float bias2[128];
    __shared__ float bias3[96];
    __shared__ float w4l[96];

    const int tid = threadIdx.x;
    const int wv = tid >> 6;
    const int lane = tid & 63;
    const int g = lane >> 4, col = lane & 15;
    const int swz = (col & 7) << 3;    // f16-index swizzle bits 3..5

    {   // cooperative staging: 80KB frags + biases
        float4* wl4 = (float4*)wlds;
        for (int i = tid; i < 5120; i += 512) wl4[i] = fragsv[i];
        for (int i = tid; i < 128; i += 512) bias2[i] = b2[i];
        for (int i = tid; i < 96; i += 512) { bias3[i] = b3[i]; w4l[i] = w4[i]; }
    }
    __syncthreads();
    const float b4v = b4[0];

    f16* ah = acth[wv];
    u32* ibA = ibuf[wv][0];
    u32* ibB = ibuf[wv][1];

    const int wtotal = 31250;          // 1e6 / 32
    int wg = blockIdx.x * 8 + wv;
    const int wstride = gridDim.x * 8;

    // prefetch registers (per tile): kc0 chunks, kc1 chunks, tail, coords
    f32x2v Ac0[4], Ac1[4], Ae, Axv; float Asv;
    f32x2v Bc0[4], Bc1[4], Be, Bxv; float Bsv;

    auto LOADT = [&](int pt0, f32x2v* c0, f32x2v* c1, f32x2v& e, f32x2v& xv, float& sv) {
        const float* base = sse + (long)(pt0 + col) * 50;
#pragma unroll
        for (int q = 0; q < 4; q++) c0[q] = *(const f32x2v*)(base + 8 * g + 2 * q);
        if (g < 2) {
#pragma unroll
            for (int q = 0; q < 4; q++) c1[q] = *(const f32x2v*)(base + 32 + 8 * g + 2 * q);
        } else if (g == 2) {
            e = *(const f32x2v*)(base + 48);
            sv = s[pt0 + col];
        }
        xv = *(const f32x2v*)(x + 2 * (pt0 + col));
    };

    // per-lane interp: pt=col, channels 4g..4g+3 -> ibuf u32 slots 2g,2g+1
    auto INTERP = [&](f32x2v xv, u32* ib) {
        float gx = fminf(fmaxf(xv.x, EPS_), 1.f - EPS_) * 127.f;
        float gy = fminf(fmaxf(xv.y, EPS_), 1.f - EPS_) * 127.f;
        float fx0 = floorf(gx), fy0 = floorf(gy);
        int ix0 = (int)fx0, iy0 = (int)fy0;
        int ix1 = min(ix0 + 1, 127), iy1 = min(iy0 + 1, 127);
        float wx = gx - fx0, wy = gy - fy0;
        const f32x4v* A4 = (const f32x4v*)Amat;
        f32x4v f00 = A4[(iy0 * 128 + ix0) * 4 + g];
        f32x4v f10 = A4[(iy0 * 128 + ix1) * 4 + g];
        f32x4v f01 = A4[(iy1 * 128 + ix0) * 4 + g];
        f32x4v f11 = A4[(iy1 * 128 + ix1) * 4 + g];
        float w00 = (1.f - wx) * (1.f - wy), w10 = wx * (1.f - wy);
        float w01 = (1.f - wx) * wy, w11 = wx * wy;
        f32x4v r = f00 * w00 + f10 * w10 + f01 * w01 + f11 * w11;
        uint2 uv;
        uv.x = bc32(pk2(r.x, r.y));
        uv.y = bc32(pk2(r.z, r.w));
        *(uint2*)(ib + col * 12 + 2 * g) = uv;
    };

    // build 3 B-frags for one tile from prefetched regs + interp buffer
    auto BUILD = [&](f32x2v* c0, f32x2v* c1, f32x2v e, f32x2v xv, float sv,
                     const u32* ib, f16x8* bf) {
        bf[0] = cvt8x2(c0[0], c0[1], c0[2], c0[3]);
        if (g < 2) {
            bf[1] = cvt8x2(c1[0], c1[1], c1[2], c1[3]);
        } else if (g == 2) {
            f16x8 t = zero8();
            t[0] = (f16)e.x; t[1] = (f16)e.y;          // sse 48,49
            t[2] = (f16)xv.x; t[3] = (f16)xv.y;        // x0,x1
            t[4] = (f16)sv;                            // s
            bf[1] = t;
        } else {
            bf[1] = *(const f16x8*)(ib + col * 12);    // interp ch 0..7
        }
        if (g == 0) {
            bf[2] = *(const f16x8*)(ib + col * 12 + 4);  // interp ch 8..15
        } else if (g == 1) {
            f16x8 t = zero8();
            t[0] = (f16)1.f;                           // k=72 bias slot
            bf[2] = t;
        } else {
            bf[2] = zero8();
        }
    };

    // C-layout (out=16mf+4g+r, pt=col) -> relu(+bias) -> acth -> B-frags of h
    auto TRANS = [&](f32x4v* acc, const float* bias, f16x8* hbf) {
#pragma unroll
        for (int mf = 0; mf < 8; mf++) {
            f32x4v v = acc[mf];
            if (bias) {
                f32x4v bb = *(const f32x4v*)&bias[mf * 16 + g * 4];
                v = v + bb;
            }
            uint2 uv;
            uv.x = bc32(pk2(fmaxf(v.x, 0.f), fmaxf(v.y, 0.f)));
            uv.y = bc32(pk2(fmaxf(v.z, 0.f), fmaxf(v.w, 0.f)));
            *(uint2*)&ah[(col * 128 + mf * 16 + g * 4) ^ swz] = uv;
        }
#pragma unroll
        for (int kc = 0; kc < 4; kc++)
            hbf[kc] = *(const f16x8*)&ah[(col * 128 + kc * 32 + g * 8) ^ swz];
    };

    auto L4OUT = [&](f32x4v* acc3, int pt0) {
        float partial = 0.f;
#pragma unroll
        for (int mf = 0; mf < 6; mf++) {
            f32x4v bb = *(const f32x4v*)&bias3[mf * 16 + g * 4];
            f32x4v wv4 = *(const f32x4v*)&w4l[mf * 16 + g * 4];
            partial += fmaxf(acc3[mf].x + bb.x, 0.f) * wv4.x;
            partial += fmaxf(acc3[mf].y + bb.y, 0.f) * wv4.y;
            partial += fmaxf(acc3[mf].z + bb.z, 0.f) * wv4.z;
            partial += fmaxf(acc3[mf].w + bb.w, 0.f) * wv4.w;
        }
        partial += __shfl_xor(partial, 16);
        partial += __shfl_xor(partial, 32);
        if (g == 0) out[pt0 + col] = partial + b4v;
    };

    if (wg < wtotal) {
        LOADT(wg * 32, Ac0, Ac1, Ae, Axv, Asv);
        LOADT(wg * 32 + 16, Bc0, Bc1, Be, Bxv, Bsv);
    }

    for (; wg < wtotal; wg += wstride) {
        const int pt0 = wg * 32;

        INTERP(Axv, ibA);
        INTERP(Bxv, ibB);

        f16x8 bfA[3], bfB[3];
        BUILD(Ac0, Ac1, Ae, Axv, Asv, ibA, bfA);
        BUILD(Bc0, Bc1, Be, Bxv, Bsv, ibB, bfB);

        // prefetch next batch (registers now free)
        int wgn = wg + wstride;
        if (wgn < wtotal) {
            LOADT(wgn * 32, Ac0, Ac1, Ae, Axv, Asv);
            LOADT(wgn * 32 + 16, Bc0, Bc1, Be, Bxv, Bsv);
        }

        // ---- Layer 1: K=96 (3 kc), 8 mf ----
        f32x4v accA[8], accB[8];
#pragma unroll
        for (int mf = 0; mf < 8; mf++) {
            accA[mf] = (f32x4v)(0.f);
            accB[mf] = (f32x4v)(0.f);
        }
#pragma unroll
        for (int kc = 0; kc < 3; kc++) {
#pragma unroll
            for (int mf = 0; mf < 8; mf++) {
                f16x8 wf = *(const f16x8*)&wlds[((mf * 3 + kc) * 64 + lane) * 8];
                accA[mf] = mfma16(wf, bfA[kc], accA[mf]);
                accB[mf] = mfma16(wf, bfB[kc], accB[mf]);
            }
        }

        f16x8 hbfA[4], hbfB[4];
        TRANS(accA, nullptr, hbfA);   // L1 bias came via k=72 slot
        TRANS(accB, nullptr, hbfB);

        // ---- Layer 2: K=128 (4 kc), 8 mf ----
        f32x4v acc2A[8], acc2B[8];
#pragma unroll
        for (int mf = 0; mf < 8; mf++) {
            acc2A[mf] = (f32x4v)(0.f);
            acc2B[mf] = (f32x4v)(0.f);
        }
#pragma unroll
        for (int kc = 0; kc < 4; kc++) {
#pragma unroll
            for (int mf = 0; mf < 8; mf++) {
                f16x8 wf = *(const f16x8*)&wlds[((24 + mf * 4 + kc) * 64 + lane) * 8];
                acc2A[mf] = mfma16(wf, hbfA[kc], acc2A[mf]);
                acc2B[mf] = mfma16(wf, hbfB[kc], acc2B[mf]);
            }
        }

        TRANS(acc2A, bias2, hbfA);
        TRANS(acc2B, bias2, hbfB);

        // ---- Layer 3: K=128 (4 kc), 6 mf ----
        f32x4v acc3A[6], acc3B[6];
#pragma unroll
        for (int mf = 0; mf < 6; mf++) {
            acc3A[mf] = (f32x4v)(0.f);
            acc3B[mf] = (f32x4v)(0.f);
        }
#pragma unroll
        for (int kc = 0; kc < 4; kc++) {
#pragma unroll
            for (int mf = 0; mf < 6; mf++) {
                f16x8 wf = *(const f16x8*)&wlds[((56 + mf * 4 + kc) * 64 + lane) * 8];
                acc3A[mf] = mfma16(wf, hbfA[kc], acc3A[mf]);
                acc3B[mf] = mfma16(wf, hbfB[kc], acc3B[mf]);
            }
        }

        // ---- Layer 4 + output ----
        L4OUT(acc3A, pt0);
        L4OUT(acc3B, pt0 + 16);
    }
}

// ---------------------------------------------------------------------------
extern "C" void kernel_launch(void* const* d_in, const int* in_sizes, int n_in,
                              void* d_out, int out_size, void* d_ws, size_t ws_size,
                              hipStream_t stream) {
    const float* x      = (const float*)d_in[0];
    const float* s      = (const float*)d_in[1];
    const float* sse    = (const float*)d_in[2];
    const float* sdf    = (const float*)d_in[3];
    const float* conv_w = (const float*)d_in[4];
    const float* conv_b = (const float*)d_in[5];
    const float* w1     = (const float*)d_in[6];
    const float* b1     = (const float*)d_in[7];
    const float* w2     = (const float*)d_in[8];
    const float* b2     = (const float*)d_in[9];
    const float* w3     = (const float*)d_in[10];
    const float* b3     = (const float*)d_in[11];
    const float* w4     = (const float*)d_in[12];
    const float* b4     = (const float*)d_in[13];
    float* out = (float*)d_out;

    float* pooled = (float*)d_ws;            // 32768 f32  [0, 131072) bytes
    float* A      = pooled + 32768;          // 262144 f32 [131072, 1179648)
    f16*   frags  = (f16*)d_ws;              // 80 KB, reuses pooled region
                                             // (written by pack AFTER conv reads pooled)

    pool_kernel<<<128, 256, 0, stream>>>(sdf, pooled);
    conv_kernel<<<64, 256, 0, stream>>>(pooled, conv_w, conv_b, A);
    pack_kernel<<<20, 256, 0, stream>>>(w1, b1, w2, w3, frags);
    mlp_kernel<<<256, 512, 0, stream>>>(x, s, sse, A, (const float4*)frags,
                                        b2, b3, w4, b4, out);
}